// Round 1
// baseline (1100.690 us; speedup 1.0000x reference)
//
#include <hip/hip_runtime.h>

#define NSLOT 32
#define DIM 256
#define BSZ 4096

// ============================================================================
// K1/K2: per-slot projection GEMM.
//   Y[(b*NSLOT + slot)*DIM + n] = sum_d X[slot][b][d] * W[slot][d][n]
// X: (NSLOT, BSZ, DIM) row-major, W: (NSLOT, DIM, DIM), Y: (BSZ, NSLOT, DIM)
// Tiling: BM=64, BN=64, BK=16, 256 threads, 4x4 microtile per thread.
// NOUT=2 computes two outputs (key-proj + value-proj) sharing the A (k) tile.
// ============================================================================
template<int NOUT>
__global__ __launch_bounds__(256)
void proj_kernel(const float* __restrict__ X,
                 const float* __restrict__ W1,
                 const float* __restrict__ W2,
                 float* __restrict__ Y1,
                 float* __restrict__ Y2)
{
    const int slot = blockIdx.z;
    const int m0 = blockIdx.x * 64;
    const int n0 = blockIdx.y * 64;

    const float* A  = X  + (size_t)slot * BSZ * DIM;
    const float* Wa = W1 + (size_t)slot * DIM * DIM;
    const float* Wb = (NOUT == 2) ? (W2 + (size_t)slot * DIM * DIM) : nullptr;

    // A tile stored transposed [kk][row], row-stride 68 (16B-aligned, depads banks)
    __shared__ float Al[16 * 68];
    __shared__ float W1l[16 * 64];
    __shared__ float W2l[16 * 64];

    const int tid  = threadIdx.x;
    const int tx   = tid & 15;        // output col group (0..15) -> 4 cols each
    const int ty   = tid >> 4;        // output row group (0..15) -> 4 rows each
    const int lrow = tid >> 2;        // A-load row   (0..63)
    const int lcol = (tid & 3) << 2;  // A-load col4  (0,4,8,12)
    const int wrow = tid >> 4;        // W-load row   (0..15)
    const int wcol = (tid & 15) << 2; // W-load col4  (0..60)

    float acc1[4][4] = {{0.f}};
    float acc2[4][4] = {{0.f}};

    for (int k0 = 0; k0 < DIM; k0 += 16) {
        // global loads first (overlap with previous compute before barrier)
        const float4 av = *(const float4*)(A  + (size_t)(m0 + lrow) * DIM + k0 + lcol);
        const float4 w1 = *(const float4*)(Wa + (size_t)(k0 + wrow) * DIM + n0 + wcol);
        float4 w2 = {0.f, 0.f, 0.f, 0.f};
        if (NOUT == 2)
            w2 = *(const float4*)(Wb + (size_t)(k0 + wrow) * DIM + n0 + wcol);

        __syncthreads();   // previous iteration's LDS reads complete
        Al[(lcol + 0) * 68 + lrow] = av.x;
        Al[(lcol + 1) * 68 + lrow] = av.y;
        Al[(lcol + 2) * 68 + lrow] = av.z;
        Al[(lcol + 3) * 68 + lrow] = av.w;
        *(float4*)(W1l + wrow * 64 + wcol) = w1;
        if (NOUT == 2)
            *(float4*)(W2l + wrow * 64 + wcol) = w2;
        __syncthreads();

        #pragma unroll
        for (int kk = 0; kk < 16; ++kk) {
            const float4 a4 = *(const float4*)(Al  + kk * 68 + ty * 4);
            const float4 b4 = *(const float4*)(W1l + kk * 64 + tx * 4);
            const float ar[4] = {a4.x, a4.y, a4.z, a4.w};
            const float br[4] = {b4.x, b4.y, b4.z, b4.w};
            #pragma unroll
            for (int r = 0; r < 4; ++r)
                #pragma unroll
                for (int c = 0; c < 4; ++c)
                    acc1[r][c] = fmaf(ar[r], br[c], acc1[r][c]);
            if (NOUT == 2) {
                const float4 c4 = *(const float4*)(W2l + kk * 64 + tx * 4);
                const float cr[4] = {c4.x, c4.y, c4.z, c4.w};
                #pragma unroll
                for (int r = 0; r < 4; ++r)
                    #pragma unroll
                    for (int c = 0; c < 4; ++c)
                        acc2[r][c] = fmaf(ar[r], cr[c], acc2[r][c]);
            }
        }
    }

    #pragma unroll
    for (int r = 0; r < 4; ++r) {
        const int row = m0 + ty * 4 + r;
        const size_t base = ((size_t)row * NSLOT + slot) * DIM + n0 + tx * 4;
        const float4 o1 = {acc1[r][0], acc1[r][1], acc1[r][2], acc1[r][3]};
        *(float4*)(Y1 + base) = o1;
        if (NOUT == 2) {
            const float4 o2 = {acc2[r][0], acc2[r][1], acc2[r][2], acc2[r][3]};
            *(float4*)(Y2 + base) = o2;
        }
    }
}

// ============================================================================
// K3: per-batch-row fused logits -> softmax -> PV.
// One block (256 thr) per batch row b. keyp/value rows staged in LDS with
// row-stride 260 floats (16B-aligned float4, breaks the stride-256 bank wall).
// out[(n*BSZ + b)*DIM + o]
// ============================================================================
__global__ __launch_bounds__(256)
void attn_kernel(const float* __restrict__ Qp,
                 const float* __restrict__ Kp,
                 const float* __restrict__ Vp,
                 float* __restrict__ out)
{
    const int b = blockIdx.x;
    const int tid = threadIdx.x;

    __shared__ float kl[32 * 260];
    __shared__ float vl[32 * 260];
    __shared__ float att[32 * 33];

    const float* qb = Qp + (size_t)b * NSLOT * DIM;
    const float* kb = Kp + (size_t)b * NSLOT * DIM;
    const float* vb = Vp + (size_t)b * NSLOT * DIM;

    // stage keyp + value: 2 x 32x256 floats as float4s (2048 each, 8 iters)
    #pragma unroll
    for (int i = 0; i < 8; ++i) {
        const int f  = i * 256 + tid;   // float4 index 0..2047
        const int m  = f >> 6;          // key slot
        const int a4 = (f & 63) << 2;   // dim offset
        *(float4*)(kl + m * 260 + a4) = *(const float4*)(kb + m * 256 + a4);
        *(float4*)(vl + m * 260 + a4) = *(const float4*)(vb + m * 256 + a4);
    }
    __syncthreads();

    // logits: 32x32 = 1024 dot products of length 256; 4 per thread
    #pragma unroll
    for (int p4 = 0; p4 < 4; ++p4) {
        const int p = p4 * 256 + tid;
        const int n = p >> 5, m = p & 31;
        const float* qrow = qb + n * 256;   // broadcast within lane groups
        const float* krow = kl + m * 260;
        float acc = 0.f;
        #pragma unroll 8
        for (int a = 0; a < 64; ++a) {
            const float4 qv = *(const float4*)(qrow + a * 4);
            const float4 kv = *(const float4*)(krow + a * 4);
            acc = fmaf(qv.x, kv.x, acc);
            acc = fmaf(qv.y, kv.y, acc);
            acc = fmaf(qv.z, kv.z, acc);
            acc = fmaf(qv.w, kv.w, acc);
        }
        att[n * 33 + m] = acc * 0.0625f;   // / sqrt(256)
    }
    __syncthreads();

    // softmax over m for each of 32 rows (one lane per row; stride-33 = bank-clean)
    if (tid < 32) {
        const int n = tid;
        float mx = -1e30f;
        #pragma unroll
        for (int m = 0; m < 32; ++m) mx = fmaxf(mx, att[n * 33 + m]);
        float s = 0.f;
        #pragma unroll
        for (int m = 0; m < 32; ++m) {
            const float e = __expf(att[n * 33 + m] - mx);
            att[n * 33 + m] = e;
            s += e;
        }
        const float inv = 1.f / s;
        #pragma unroll
        for (int m = 0; m < 32; ++m) att[n * 33 + m] *= inv;
    }
    __syncthreads();

    // PV: out[n][b][tid] = sum_m att[n][m] * value[m][tid]
    #pragma unroll 4
    for (int n = 0; n < 32; ++n) {
        float acc = 0.f;
        #pragma unroll
        for (int m = 0; m < 32; ++m)
            acc = fmaf(att[n * 33 + m], vl[m * 260 + tid], acc);
        out[((size_t)n * BSZ + b) * DIM + tid] = acc;
    }
}

// ============================================================================
extern "C" void kernel_launch(void* const* d_in, const int* in_sizes, int n_in,
                              void* d_out, int out_size, void* d_ws, size_t ws_size,
                              hipStream_t stream)
{
    const float* q  = (const float*)d_in[0];  // (32, 4096, 256)
    const float* k  = (const float*)d_in[1];  // (32, 4096, 256)
    const float* qw = (const float*)d_in[2];  // (32, 256, 256)
    const float* kw = (const float*)d_in[3];  // (32, 256, 256)
    const float* vw = (const float*)d_in[4];  // (32, 256, 256)
    float* out = (float*)d_out;               // (32, 4096, 256)

    // workspace: query / keyp / value intermediates, each (BSZ, NSLOT, DIM) f32
    // = 3 * 128 MB = 384 MB required.
    float* ws = (float*)d_ws;
    const size_t per = (size_t)BSZ * NSLOT * DIM;
    float* q_ws  = ws;
    float* kp_ws = ws + per;
    float* v_ws  = ws + 2 * per;

    dim3 grid(BSZ / 64, DIM / 64, NSLOT);   // (64, 4, 32)
    proj_kernel<2><<<grid, dim3(256), 0, stream>>>(k, kw, vw, kp_ws, v_ws);
    proj_kernel<1><<<grid, dim3(256), 0, stream>>>(q, qw, nullptr, q_ws, nullptr);
    attn_kernel<<<dim3(BSZ), dim3(256), 0, stream>>>(q_ws, kp_ws, v_ws, out);
}

// Round 3
// 635.472 us; speedup vs baseline: 1.7321x; 1.7321x over previous
//
#include <hip/hip_runtime.h>

#define NSLOT 32
#define DIM 256
#define BSZ 4096

typedef _Float16 f16;
typedef f16 f16x4 __attribute__((ext_vector_type(4)));
typedef f16 f16x8 __attribute__((ext_vector_type(8)));
typedef float f32x4 __attribute__((ext_vector_type(4)));

// ============================================================================
// K0: weight transpose + f32->f16 convert.
//   W[slot][k][n] f32  ->  Wt[slot][n][k] f16
// grid (DIM/32, DIM/32, 3*NSLOT), 256 threads, 32x32 LDS transpose tile.
// ============================================================================
__global__ __launch_bounds__(256)
void wt_kernel(const float* __restrict__ qw, const float* __restrict__ kw,
               const float* __restrict__ vw,
               f16* __restrict__ wtq, f16* __restrict__ wtk, f16* __restrict__ wtv)
{
    const int which = blockIdx.z >> 5;
    const int slot  = blockIdx.z & 31;
    const float* W = (which == 0) ? qw : (which == 1) ? kw : vw;
    f16*         T = (which == 0) ? wtq : (which == 1) ? wtk : wtv;
    W += (size_t)slot * DIM * DIM;
    T += (size_t)slot * DIM * DIM;

    const int n0 = blockIdx.x * 32;
    const int k0 = blockIdx.y * 32;

    __shared__ float t[32][33];
    const int tid = threadIdx.x;

    {   // load 32x32 f32 tile (coalesced along n)
        const int kk = tid >> 3, nc = (tid & 7) << 2;
        const float4 v = *(const float4*)(W + (size_t)(k0 + kk) * DIM + n0 + nc);
        t[kk][nc + 0] = v.x; t[kk][nc + 1] = v.y;
        t[kk][nc + 2] = v.z; t[kk][nc + 3] = v.w;
    }
    __syncthreads();
    {   // store transposed as f16 (contiguous along k)
        const int nn = tid >> 3, kc = (tid & 7) << 2;
        f16x4 h;
        h[0] = (f16)t[kc + 0][nn]; h[1] = (f16)t[kc + 1][nn];
        h[2] = (f16)t[kc + 2][nn]; h[3] = (f16)t[kc + 3][nn];
        *(f16x4*)(T + (size_t)(n0 + nn) * DIM + k0 + kc) = h;
    }
}

// ============================================================================
// K1/K2: per-slot projection GEMM via fp16 MFMA (fp32 accumulate).
//   Y[(b*NSLOT+slot)*DIM + n] = sum_d X[slot][b][d] * W[slot][d][n]
// X f32 (NSLOT,BSZ,DIM); Wt f16 [slot][n][k] (pre-transposed); Y f16.
// Block tile 128x128, BK=32, 256 thr = 4 waves (2x2 of 64x64).
// Grid: 2048 linear blocks, XCD-bijective swizzle pairing n-blocks of the
// same (slot,m0) for A-tile L2 reuse.
// ============================================================================
template<int NOUT>
__global__ __launch_bounds__(256)
void proj_mfma(const float* __restrict__ X,
               const f16* __restrict__ Wt1, const f16* __restrict__ Wt2,
               f16* __restrict__ Y1, f16* __restrict__ Y2)
{
    // bijective XCD swizzle: 2048 blocks, 256 consecutive works per XCD
    const int lin  = blockIdx.x;
    const int work = (lin & 7) * 256 + (lin >> 3);
    const int n0b  = work & 1;          // n block (0/1)
    const int m0b  = (work >> 1) & 31;  // m block
    const int slot = work >> 6;

    const int m0 = m0b * 128, n0 = n0b * 128;

    const float* A  = X   + (size_t)slot * BSZ * DIM;
    const f16*   B1 = Wt1 + (size_t)slot * DIM * DIM;
    const f16*   B2 = (NOUT == 2) ? (Wt2 + (size_t)slot * DIM * DIM) : nullptr;

    // padded stride 40 halves (80 B): 16B-aligned rows, ~2-way banks max
    __shared__ f16 Al [128 * 40];
    __shared__ f16 Bl1[128 * 40];
    __shared__ f16 Bl2[(NOUT == 2) ? 128 * 40 : 8];

    const int tid  = threadIdx.x;
    const int wave = tid >> 6;
    const int lane = tid & 63;
    const int wm   = wave >> 1, wn = wave & 1;      // wave grid 2x2
    const int lr   = lane & 15;
    const int lk   = (lane >> 4) * 8;

    f32x4 acc1[4][4], acc2[4][4];
    #pragma unroll
    for (int i = 0; i < 4; ++i)
        #pragma unroll
        for (int j = 0; j < 4; ++j) {
            acc1[i][j] = (f32x4){0.f, 0.f, 0.f, 0.f};
            if (NOUT == 2) acc2[i][j] = (f32x4){0.f, 0.f, 0.f, 0.f};
        }

    for (int k0 = 0; k0 < DIM; k0 += 32) {
        // ---- global loads to regs (before barrier) ----
        float4 a4[4];
        #pragma unroll
        for (int it = 0; it < 4; ++it) {
            const int i = it * 256 + tid;            // float4 chunk 0..1023
            const int r = i >> 3, kc4 = (i & 7) << 2;
            a4[it] = *(const float4*)(A + (size_t)(m0 + r) * DIM + k0 + kc4);
        }
        f16x8 b4a[2], b4b[2];
        #pragma unroll
        for (int it = 0; it < 2; ++it) {
            const int i = it * 256 + tid;            // f16x8 chunk 0..511
            const int r = i >> 2, kc8 = (i & 3) << 3;
            b4a[it] = *(const f16x8*)(B1 + (size_t)(n0 + r) * DIM + k0 + kc8);
            if (NOUT == 2)
                b4b[it] = *(const f16x8*)(B2 + (size_t)(n0 + r) * DIM + k0 + kc8);
        }

        __syncthreads();   // previous iter's LDS reads done
        #pragma unroll
        for (int it = 0; it < 4; ++it) {
            const int i = it * 256 + tid;
            const int r = i >> 3, kc4 = (i & 7) << 2;
            f16x4 h;
            h[0] = (f16)a4[it].x; h[1] = (f16)a4[it].y;
            h[2] = (f16)a4[it].z; h[3] = (f16)a4[it].w;
            *(f16x4*)(Al + r * 40 + kc4) = h;
        }
        #pragma unroll
        for (int it = 0; it < 2; ++it) {
            const int i = it * 256 + tid;
            const int r = i >> 2, kc8 = (i & 3) << 3;
            *(f16x8*)(Bl1 + r * 40 + kc8) = b4a[it];
            if (NOUT == 2) *(f16x8*)(Bl2 + r * 40 + kc8) = b4b[it];
        }
        __syncthreads();

        // ---- fragments + MFMA ----
        f16x8 af[4], bf1[4], bf2[4];
        #pragma unroll
        for (int mi = 0; mi < 4; ++mi)
            af[mi] = *(const f16x8*)(Al + (wm * 64 + mi * 16 + lr) * 40 + lk);
        #pragma unroll
        for (int ni = 0; ni < 4; ++ni) {
            bf1[ni] = *(const f16x8*)(Bl1 + (wn * 64 + ni * 16 + lr) * 40 + lk);
            if (NOUT == 2)
                bf2[ni] = *(const f16x8*)(Bl2 + (wn * 64 + ni * 16 + lr) * 40 + lk);
        }
        #pragma unroll
        for (int mi = 0; mi < 4; ++mi)
            #pragma unroll
            for (int ni = 0; ni < 4; ++ni) {
                acc1[mi][ni] = __builtin_amdgcn_mfma_f32_16x16x32_f16(
                    af[mi], bf1[ni], acc1[mi][ni], 0, 0, 0);
                if (NOUT == 2)
                    acc2[mi][ni] = __builtin_amdgcn_mfma_f32_16x16x32_f16(
                        af[mi], bf2[ni], acc2[mi][ni], 0, 0, 0);
            }
    }

    // ---- epilogue: C/D layout col=lane&15, row=(lane>>4)*4+j ----
    #pragma unroll
    for (int mi = 0; mi < 4; ++mi)
        #pragma unroll
        for (int ni = 0; ni < 4; ++ni) {
            const int col = n0 + wn * 64 + ni * 16 + lr;
            #pragma unroll
            for (int j = 0; j < 4; ++j) {
                const int row = m0 + wm * 64 + mi * 16 + (lane >> 4) * 4 + j;
                const size_t base = ((size_t)row * NSLOT + slot) * DIM + col;
                Y1[base] = (f16)acc1[mi][ni][j];
                if (NOUT == 2) Y2[base] = (f16)acc2[mi][ni][j];
            }
        }
}

// ============================================================================
// K3: per-batch-row fused logits -> softmax -> PV (f16 inputs, f32 out).
// ============================================================================
__global__ __launch_bounds__(256)
void attn_kernel(const f16* __restrict__ Qp,
                 const f16* __restrict__ Kp,
                 const f16* __restrict__ Vp,
                 float* __restrict__ out)
{
    const int b = blockIdx.x;
    const int tid = threadIdx.x;

    __shared__ float kl[32 * 260];   // K rows as f32 (cvt once at staging)
    __shared__ f16   vl[32 * 264];   // V rows as f16
    __shared__ float att[32 * 33];

    const f16* qb = Qp + (size_t)b * NSLOT * DIM;
    const f16* kb = Kp + (size_t)b * NSLOT * DIM;
    const f16* vb = Vp + (size_t)b * NSLOT * DIM;

    // stage K (f16->f32) and V (f16 copy): 1024 f16x8 chunks each
    #pragma unroll
    for (int it = 0; it < 4; ++it) {
        const int c = it * 256 + tid;
        const int m = c >> 5, c8 = (c & 31) << 3;
        const f16x8 kv = *(const f16x8*)(kb + m * 256 + c8);
        float4 lo = {(float)kv[0], (float)kv[1], (float)kv[2], (float)kv[3]};
        float4 hi = {(float)kv[4], (float)kv[5], (float)kv[6], (float)kv[7]};
        *(float4*)(kl + m * 260 + c8)     = lo;
        *(float4*)(kl + m * 260 + c8 + 4) = hi;
        *(f16x8*)(vl + m * 264 + c8) = *(const f16x8*)(vb + m * 256 + c8);
    }
    __syncthreads();

    // logits: 1024 dots of length 256; 4 per thread
    #pragma unroll
    for (int p4 = 0; p4 < 4; ++p4) {
        const int p = p4 * 256 + tid;
        const int n = p >> 5, m = p & 31;
        const f16*   qrow = qb + n * 256;
        const float* krow = kl + m * 260;
        float acc = 0.f;
        #pragma unroll 4
        for (int a = 0; a < 16; ++a) {
            const f16x8 q0 = *(const f16x8*)(qrow + a * 16);
            const f16x8 q1 = *(const f16x8*)(qrow + a * 16 + 8);
            const float4 k0 = *(const float4*)(krow + a * 16);
            const float4 k1 = *(const float4*)(krow + a * 16 + 4);
            const float4 k2 = *(const float4*)(krow + a * 16 + 8);
            const float4 k3 = *(const float4*)(krow + a * 16 + 12);
            acc = fmaf((float)q0[0], k0.x, acc);
            acc = fmaf((float)q0[1], k0.y, acc);
            acc = fmaf((float)q0[2], k0.z, acc);
            acc = fmaf((float)q0[3], k0.w, acc);
            acc = fmaf((float)q0[4], k1.x, acc);
            acc = fmaf((float)q0[5], k1.y, acc);
            acc = fmaf((float)q0[6], k1.z, acc);
            acc = fmaf((float)q0[7], k1.w, acc);
            acc = fmaf((float)q1[0], k2.x, acc);
            acc = fmaf((float)q1[1], k2.y, acc);
            acc = fmaf((float)q1[2], k2.z, acc);
            acc = fmaf((float)q1[3], k2.w, acc);
            acc = fmaf((float)q1[4], k3.x, acc);
            acc = fmaf((float)q1[5], k3.y, acc);
            acc = fmaf((float)q1[6], k3.z, acc);
            acc = fmaf((float)q1[7], k3.w, acc);
        }
        att[n * 33 + m] = acc * 0.0625f;   // / sqrt(256)
    }
    __syncthreads();

    // softmax per row (32 lanes, one row each)
    if (tid < 32) {
        const int n = tid;
        float mx = -1e30f;
        #pragma unroll
        for (int m = 0; m < 32; ++m) mx = fmaxf(mx, att[n * 33 + m]);
        float s = 0.f;
        #pragma unroll
        for (int m = 0; m < 32; ++m) {
            const float e = __expf(att[n * 33 + m] - mx);
            att[n * 33 + m] = e;
            s += e;
        }
        const float inv = 1.f / s;
        #pragma unroll
        for (int m = 0; m < 32; ++m) att[n * 33 + m] *= inv;
    }
    __syncthreads();

    // PV: hoist value column into regs, 32 reuses each
    float vreg[32];
    #pragma unroll
    for (int m = 0; m < 32; ++m) vreg[m] = (float)vl[m * 264 + tid];

    #pragma unroll 4
    for (int n = 0; n < 32; ++n) {
        float acc = 0.f;
        #pragma unroll
        for (int m = 0; m < 32; ++m)
            acc = fmaf(att[n * 33 + m], vreg[m], acc);
        out[((size_t)n * BSZ + b) * DIM + tid] = acc;
    }
}

// ============================================================================
extern "C" void kernel_launch(void* const* d_in, const int* in_sizes, int n_in,
                              void* d_out, int out_size, void* d_ws, size_t ws_size,
                              hipStream_t stream)
{
    const float* q  = (const float*)d_in[0];
    const float* k  = (const float*)d_in[1];
    const float* qw = (const float*)d_in[2];
    const float* kw = (const float*)d_in[3];
    const float* vw = (const float*)d_in[4];
    float* out = (float*)d_out;

    // workspace layout (f16):
    //   Wt q/k/v : 3 * 32*256*256        = 3 * 2.10 M halves
    //   q/kp/v   : 3 * 4096*32*256       = 3 * 33.6 M halves
    f16* ws = (f16*)d_ws;
    const size_t wsz = (size_t)NSLOT * DIM * DIM;
    const size_t psz = (size_t)BSZ * NSLOT * DIM;
    f16* wtq = ws;
    f16* wtk = wtq + wsz;
    f16* wtv = wtk + wsz;
    f16* q_ws  = wtv + wsz;
    f16* kp_ws = q_ws + psz;
    f16* v_ws  = kp_ws + psz;

    wt_kernel<<<dim3(DIM / 32, DIM / 32, 3 * NSLOT), dim3(256), 0, stream>>>(
        qw, kw, vw, wtq, wtk, wtv);

    proj_mfma<2><<<dim3(2048), dim3(256), 0, stream>>>(k, wtk, wtv, kp_ws, v_ws);
    proj_mfma<1><<<dim3(2048), dim3(256), 0, stream>>>(q, wtq, nullptr, q_ws, nullptr);

    attn_kernel<<<dim3(BSZ), dim3(256), 0, stream>>>(q_ws, kp_ws, v_ws, out);
}